// Round 5
// baseline (192.461 us; speedup 1.0000x reference)
//
#include <hip/hip_runtime.h>
#include <math.h>

// Problem constants
constexpr int Bb = 256;
constexpr int Ll = 512;
constexpr int Dd = 768;
constexpr int Pp = 30;
constexpr int Kk = 4;
constexpr int LOUT = Kk + Ll;          // 516
constexpr int D4   = Dd / 4;           // 192 float4 per row
constexpr int TPB  = 768;              // 12 waves; 4 rows of float4 per pass
constexpr int ITER = Ll / 4;           // 128 passes per thread

typedef float f32x4 __attribute__((ext_vector_type(4)));

// d_out layout (float elements): prompted_embedding, similarity, reduce_sim, idx(as float)
constexpr size_t SIM_OFF = (size_t)Bb * LOUT * Dd;        // 101,449,728
constexpr size_t RS_OFF  = SIM_OFF + (size_t)Bb * Pp;     // +7680
constexpr size_t IDX_OFF = RS_OFF + 1;                    // +1

// ---------------------------------------------------------------------------
// One block per batch: copy 512x768 floats (coalesced, NT, 8-deep) while
// accumulating per-column sums in registers; then the whole per-batch tail
// (mean -> x_norm -> fused prompt-norm dots -> top-4 -> outputs) intra-block.
// No cross-block data handoff => no XCD coherence hazard.
__global__ __launch_bounds__(TPB)
void fused_kernel(const f32x4* __restrict__ x,
                  const float* __restrict__ prompt,
                  float* __restrict__ out,
                  float* __restrict__ red) {
    __shared__ f32x4  part_lds[4][D4];   // 12 KB
    __shared__ float  xn[Dd];            // 3 KB
    __shared__ float  sims[Pp];
    __shared__ int    tidx[Kk];
    __shared__ double smem[3];

    const int b   = blockIdx.x;
    const int t   = threadIdx.x;         // 0..767
    const int r0  = t / D4;              // 0..3 row offset within pass
    const int col = t % D4;              // fixed float4 column

    // ---- Phase 1: streaming copy + in-register column sums ----
    {
        const f32x4* src = x           + (size_t)(b * Ll + r0) * D4 + col;
        f32x4*       dst = (f32x4*)out + (size_t)(b * LOUT + Kk + r0) * D4 + col;
        f32x4 acc = {0.f, 0.f, 0.f, 0.f};
        for (int i0 = 0; i0 < ITER; i0 += 8) {
            f32x4 v[8];
#pragma unroll
            for (int j = 0; j < 8; ++j)
                v[j] = __builtin_nontemporal_load(src + (size_t)(i0 + j) * 4 * D4);
#pragma unroll
            for (int j = 0; j < 8; ++j) {
                __builtin_nontemporal_store(v[j], dst + (size_t)(i0 + j) * 4 * D4);
                acc += v[j];
            }
        }
        part_lds[r0][col] = acc;
    }
    __syncthreads();

    // ---- Phase 2: mean + sum-of-squares (threads 0..191, waves 0..2) ----
    double md[4];
    double ssl = 0.0;
    if (t < D4) {
        const f32x4 s0 = part_lds[0][t], s1 = part_lds[1][t],
                    s2 = part_lds[2][t], s3 = part_lds[3][t];
#pragma unroll
        for (int j = 0; j < 4; ++j) {
            const double m = ((double)s0[j] + (double)s1[j] +
                              (double)s2[j] + (double)s3[j]) * (1.0 / Ll);
            md[j] = m;
            ssl += m * m;
        }
    }
    for (int off = 32; off > 0; off >>= 1) ssl += __shfl_down(ssl, off, 64);
    if (t < D4 && (t & 63) == 0) smem[t >> 6] = ssl;
    __syncthreads();
    const double ssum = smem[0] + smem[1] + smem[2];
    const double rs = 1.0 / sqrt(fmax(ssum, 1e-12));
    if (t < D4) {
#pragma unroll
        for (int j = 0; j < 4; ++j)
            xn[4 * t + j] = (float)(md[j] * rs);
    }
    __syncthreads();

    // ---- similarity with fused prompt normalization: 8 lanes per prompt ----
    if (t < Pp * 8) {
        const int p = t >> 3;
        const int g = t & 7;
        double dot = 0.0, pss = 0.0;
        for (int i = g; i < Dd; i += 8) {
            const double pv = (double)prompt[p * Dd + i];
            dot += (double)xn[i] * pv;
            pss += pv * pv;
        }
#pragma unroll
        for (int off = 4; off > 0; off >>= 1) {
            dot += __shfl_down(dot, off, 8);
            pss += __shfl_down(pss, off, 8);
        }
        if (g == 0) {
            const float sv = (float)(dot / sqrt(fmax(pss, 1e-12)));
            sims[p] = sv;
            out[SIM_OFF + (size_t)b * Pp + p] = sv;
        }
    }
    __syncthreads();

    // ---- top-4 (strict > keeps earliest index on ties, matching lax.top_k) ----
    if (t == 0) {
        float sv[Pp];
        for (int p = 0; p < Pp; ++p) sv[p] = sims[p];
        double rsum = 0.0;
        for (int k = 0; k < Kk; ++k) {
            float best = -INFINITY;
            int   bi   = 0;
            for (int p = 0; p < Pp; ++p)
                if (sv[p] > best) { best = sv[p]; bi = p; }
            tidx[k] = bi;
            out[IDX_OFF + (size_t)b * Kk + k] = (float)bi;
            rsum += (double)best;
            sv[bi] = -INFINITY;
        }
        red[b] = (float)rsum;
    }
    __syncthreads();

    // ---- batched_prompt: out[b, k, :] = prompt[tidx[k], :]; 768 = 4*192 ----
    {
        const int k  = t / D4;           // 0..3
        const int c2 = t % D4;
        ((f32x4*)out)[(size_t)(b * LOUT + k) * D4 + c2] =
            ((const f32x4*)prompt)[(size_t)tidx[k] * D4 + c2];
    }
}

// ---------------------------------------------------------------------------
// reduce_sim = sum_b red[b] / B. 1 block x 256. Kernel boundary provides the
// cross-block visibility (known-good, no fence games).
__global__ void finalize_kernel(const float* __restrict__ red,
                                float* __restrict__ out) {
    __shared__ double smem[4];
    const int t = threadIdx.x;
    double v = (double)red[t];
    for (int off = 32; off > 0; off >>= 1) v += __shfl_down(v, off, 64);
    if ((t & 63) == 0) smem[t >> 6] = v;
    __syncthreads();
    if (t == 0)
        out[RS_OFF] = (float)((smem[0] + smem[1] + smem[2] + smem[3]) * (1.0 / Bb));
}

// ---------------------------------------------------------------------------
extern "C" void kernel_launch(void* const* d_in, const int* in_sizes, int n_in,
                              void* d_out, int out_size, void* d_ws, size_t ws_size,
                              hipStream_t stream) {
    const float* x_embed = (const float*)d_in[0];   // [256,512,768]
    const float* prompt  = (const float*)d_in[1];   // [30,768]
    float* out = (float*)d_out;
    float* red = (float*)d_ws;                      // 256 floats

    fused_kernel<<<Bb, TPB, 0, stream>>>(
        (const f32x4*)x_embed, prompt, out, red);

    finalize_kernel<<<1, Bb, 0, stream>>>(red, out);
}